// Round 2
// baseline (25015.439 us; speedup 1.0000x reference)
//
#include <hip/hip_runtime.h>
#include <hip/hip_cooperative_groups.h>
#include <math.h>

namespace cg = cooperative_groups;

#define Bb 64
#define Tt 256
#define Vv 4096
#define Ee 512
#define Hh 1024

// ---------------- input projection: AtT[t][n][b] = sum_e wte[x[b,t]][e]*W[n][e] + bias[n]
__global__ __launch_bounds__(256) void k_proj(const int* __restrict__ x,
                                              const float* __restrict__ wte,
                                              const float* __restrict__ W,
                                              const float* __restrict__ bias,
                                              float* __restrict__ AtT) {
  __shared__ float As[16][132];
  __shared__ float Bs[16][132];
  int tid = threadIdx.x;
  int m0 = blockIdx.x * 128;
  int n0 = blockIdx.y * 128;
  int tm = tid & 15, tn = tid >> 4;
  float acc[8][8];
#pragma unroll
  for (int i = 0; i < 8; ++i)
#pragma unroll
    for (int j = 0; j < 8; ++j) acc[i][j] = 0.f;

  for (int k0 = 0; k0 < Ee; k0 += 16) {
#pragma unroll
    for (int p = 0; p < 2; ++p) {
      int id = tid + p * 256;
      int row = id >> 2, c4 = id & 3;
      int m = m0 + row;
      int tok = x[(m & 63) * Tt + (m >> 6)];
      float4 v = *(const float4*)(wte + tok * Ee + k0 + c4 * 4);
      As[c4 * 4 + 0][row] = v.x; As[c4 * 4 + 1][row] = v.y;
      As[c4 * 4 + 2][row] = v.z; As[c4 * 4 + 3][row] = v.w;
    }
#pragma unroll
    for (int p = 0; p < 2; ++p) {
      int id = tid + p * 256;
      int row = id >> 2, c4 = id & 3;
      float4 v = *(const float4*)(W + (n0 + row) * 1536 + k0 + c4 * 4);
      Bs[c4 * 4 + 0][row] = v.x; Bs[c4 * 4 + 1][row] = v.y;
      Bs[c4 * 4 + 2][row] = v.z; Bs[c4 * 4 + 3][row] = v.w;
    }
    __syncthreads();
#pragma unroll
    for (int kk = 0; kk < 16; ++kk) {
      float4 a0 = *(const float4*)&As[kk][tm * 8];
      float4 a1 = *(const float4*)&As[kk][tm * 8 + 4];
      float4 b0 = *(const float4*)&Bs[kk][tn * 8];
      float4 b1 = *(const float4*)&Bs[kk][tn * 8 + 4];
      float av[8] = {a0.x, a0.y, a0.z, a0.w, a1.x, a1.y, a1.z, a1.w};
      float bv[8] = {b0.x, b0.y, b0.z, b0.w, b1.x, b1.y, b1.z, b1.w};
#pragma unroll
      for (int i = 0; i < 8; ++i)
#pragma unroll
        for (int j = 0; j < 8; ++j)
          acc[i][j] = fmaf(av[i], bv[j], acc[i][j]);
    }
    __syncthreads();
  }
#pragma unroll
  for (int i = 0; i < 8; ++i) {
    int m = m0 + tm * 8 + i;
    int t = m >> 6, b = m & 63;
#pragma unroll
    for (int j = 0; j < 8; ++j) {
      int n = n0 + tn * 8 + j;
      AtT[(size_t)t * (Hh * Bb) + n * Bb + b] = acc[i][j] + bias[n];
    }
  }
}

// ---------------- head GEMM ------------------------------------------------------------
__global__ __launch_bounds__(256) void k_head(const float* __restrict__ A,
                                              const float* __restrict__ W,
                                              const float* __restrict__ bias,
                                              float* __restrict__ C) {
  __shared__ float As[16][132];
  __shared__ float Bs[16][132];
  int tid = threadIdx.x;
  int m0 = blockIdx.x * 128;
  int n0 = blockIdx.y * 128;
  int tm = tid & 15, tn = tid >> 4;
  float acc[8][8];
#pragma unroll
  for (int i = 0; i < 8; ++i)
#pragma unroll
    for (int j = 0; j < 8; ++j) acc[i][j] = 0.f;

  for (int k0 = 0; k0 < Hh; k0 += 16) {
#pragma unroll
    for (int p = 0; p < 2; ++p) {
      int id = tid + p * 256;
      int row = id >> 2, c4 = id & 3;
      float4 v = *(const float4*)(A + (size_t)(m0 + row) * Hh + k0 + c4 * 4);
      As[c4 * 4 + 0][row] = v.x; As[c4 * 4 + 1][row] = v.y;
      As[c4 * 4 + 2][row] = v.z; As[c4 * 4 + 3][row] = v.w;
    }
#pragma unroll
    for (int p = 0; p < 2; ++p) {
      int id = tid + p * 256;
      int row = id >> 2, c4 = id & 3;
      float4 v = *(const float4*)(W + (size_t)(n0 + row) * Hh + k0 + c4 * 4);
      Bs[c4 * 4 + 0][row] = v.x; Bs[c4 * 4 + 1][row] = v.y;
      Bs[c4 * 4 + 2][row] = v.z; Bs[c4 * 4 + 3][row] = v.w;
    }
    __syncthreads();
#pragma unroll
    for (int kk = 0; kk < 16; ++kk) {
      float4 a0 = *(const float4*)&As[kk][tm * 8];
      float4 a1 = *(const float4*)&As[kk][tm * 8 + 4];
      float4 b0 = *(const float4*)&Bs[kk][tn * 8];
      float4 b1 = *(const float4*)&Bs[kk][tn * 8 + 4];
      float av[8] = {a0.x, a0.y, a0.z, a0.w, a1.x, a1.y, a1.z, a1.w};
      float bv[8] = {b0.x, b0.y, b0.z, b0.w, b1.x, b1.y, b1.z, b1.w};
#pragma unroll
      for (int i = 0; i < 8; ++i)
#pragma unroll
        for (int j = 0; j < 8; ++j)
          acc[i][j] = fmaf(av[i], bv[j], acc[i][j]);
    }
    __syncthreads();
  }
#pragma unroll
  for (int i = 0; i < 8; ++i) {
    int m = m0 + tm * 8 + i;
#pragma unroll
    for (int jj = 0; jj < 2; ++jj) {
      int n = n0 + tn * 8 + jj * 4;
      float4 v;
      v.x = acc[i][jj * 4 + 0] + bias[n + 0];
      v.y = acc[i][jj * 4 + 1] + bias[n + 1];
      v.z = acc[i][jj * 4 + 2] + bias[n + 2];
      v.w = acc[i][jj * 4 + 3] + bias[n + 3];
      *(float4*)&C[(size_t)m * Vv + n] = v;
    }
  }
}

// ---------------- persistent cooperative recurrence ------------------------------------
// grid 256 x 512 threads (8 waves/block). Per step:
//   Phase A (blocks 0..127): preact for r (blk<64) or z (blk>=64).
//     block = 16 cols x full K, 8 waves k-split 128 each, LDS reduce.
//     r-cols: write rh = sigmoid(pre_r)*h.  z-cols: write pre_z.
//   Phase B (blocks 0..127): hbar preact (8 cols x k-split 8x128) + fused update:
//     hbt = tanh(.), z = sigmoid(pre_z), h = h + z*(hbt-h); write hT + hidden[b][t][n].
// 2 grid.sync() per step, zero atomics.
__global__ __launch_bounds__(512) void k_recur(float* __restrict__ hT,
                                               float* __restrict__ rh,
                                               float* __restrict__ pre_z,
                                               const float* __restrict__ AtT_r,
                                               const float* __restrict__ AtT_z,
                                               const float* __restrict__ AtT_b,
                                               const float* __restrict__ Wr,
                                               const float* __restrict__ Wz,
                                               const float* __restrict__ Wbar,
                                               const float* __restrict__ start,
                                               float* __restrict__ hidden) {
  cg::grid_group grid = cg::this_grid();
  __shared__ float red[8 * 16 * 64];   // 32 KB
  __shared__ float lt[8 * 65];
  int tid = threadIdx.x;
  int lane = tid & 63;
  int wv = __builtin_amdgcn_readfirstlane(tid >> 6);   // wave-uniform k-slice id
  int blk = blockIdx.x;

  {  // h0 = broadcast(start)
    int g = blk * 512 + tid;
    if (g < Hh * Bb) hT[g] = start[g >> 6];
  }
  grid.sync();

  for (int t = 0; t < Tt; ++t) {
    // ---------------- phase A: r,z preactivations ----------------
    if (blk < 128) {
      int n0 = blk * 16;                     // col group in [0,2048)
      int k0 = wv * 128;
      const float* Wsel = (blk < 64) ? Wr : Wz;
      int nb = (blk < 64) ? n0 : n0 - 1024;  // row in the selected W
      const float* hk = hT + k0 * 64 + lane;
      const float* wbase = Wsel + (size_t)nb * 1536 + 512 + k0;
      float acc[16];
#pragma unroll
      for (int c = 0; c < 16; ++c) acc[c] = 0.f;
      for (int kk = 0; kk < 128; ++kk) {
        float vh = hk[kk * 64];
#pragma unroll
        for (int c = 0; c < 16; ++c)
          acc[c] = fmaf(wbase[(size_t)c * 1536 + kk], vh, acc[c]);
      }
#pragma unroll
      for (int c = 0; c < 16; ++c) red[(wv * 16 + c) * 64 + lane] = acc[c];
      __syncthreads();
#pragma unroll
      for (int p = 0; p < 2; ++p) {
        int o = tid + p * 512;               // 1024 outputs
        int c = o >> 6, b = o & 63;
        float s = 0.f;
#pragma unroll
        for (int w = 0; w < 8; ++w) s += red[(w * 16 + c) * 64 + b];
        int n = n0 + c;
        if (blk < 64) {
          s += AtT_r[(size_t)t * 65536 + n * 64 + b];
          float sg = 1.f / (1.f + __expf(-s));
          rh[n * 64 + b] = sg * hT[n * 64 + b];
        } else {
          int nz = n - 1024;
          s += AtT_z[(size_t)t * 65536 + nz * 64 + b];
          pre_z[nz * 64 + b] = s;
        }
      }
    }
    grid.sync();
    // ---------------- phase B: hbar + fused update ----------------
    if (blk < 128) {
      int n0 = blk * 8;                      // col group in [0,1024)
      int k0 = wv * 128;
      const float* hk = rh + k0 * 64 + lane;
      const float* wbase = Wbar + (size_t)n0 * 1536 + 512 + k0;
      float acc[8];
#pragma unroll
      for (int c = 0; c < 8; ++c) acc[c] = 0.f;
      for (int kk = 0; kk < 128; ++kk) {
        float vh = hk[kk * 64];
#pragma unroll
        for (int c = 0; c < 8; ++c)
          acc[c] = fmaf(wbase[(size_t)c * 1536 + kk], vh, acc[c]);
      }
#pragma unroll
      for (int c = 0; c < 8; ++c) red[(wv * 8 + c) * 64 + lane] = acc[c];
      __syncthreads();
      {
        int c = tid >> 6, b = tid & 63;      // 512 outputs
        float s = 0.f;
#pragma unroll
        for (int w = 0; w < 8; ++w) s += red[(w * 8 + c) * 64 + b];
        int n = n0 + c;
        s += AtT_b[(size_t)t * 65536 + n * 64 + b];
        float e = __expf(2.f * s);
        float hbt = 1.f - 2.f / (e + 1.f);   // tanh, saturation-safe
        float pz = pre_z[n * 64 + b];
        float z = 1.f / (1.f + __expf(-pz));
        float ho = hT[n * 64 + b];
        float hn = ho + z * (hbt - ho);
        hT[n * 64 + b] = hn;
        lt[c * 65 + b] = hn;
      }
      __syncthreads();
      {
        int b = tid >> 3, c = tid & 7;       // coalesced hidden write
        hidden[(size_t)b * (Tt * Hh) + (size_t)t * Hh + n0 + c] = lt[c * 65 + b];
      }
    }
    grid.sync();
  }
}

extern "C" void kernel_launch(void* const* d_in, const int* in_sizes, int n_in,
                              void* d_out, int out_size, void* d_ws, size_t ws_size,
                              hipStream_t stream) {
  (void)in_sizes; (void)n_in; (void)out_size; (void)ws_size;
  const int*   x     = (const int*)  d_in[0];
  const float* start = (const float*)d_in[1];
  const float* wte   = (const float*)d_in[2];
  const float* Wr    = (const float*)d_in[3];
  const float* br    = (const float*)d_in[4];
  const float* Wbar  = (const float*)d_in[5];
  const float* bbar  = (const float*)d_in[6];
  const float* Wz    = (const float*)d_in[7];
  const float* bz    = (const float*)d_in[8];
  const float* Whead = (const float*)d_in[9];
  const float* bhead = (const float*)d_in[10];
  float* out = (float*)d_out;

  float* p = (float*)d_ws;
  float* AtT_r  = p; p += (size_t)Tt * Hh * Bb;
  float* AtT_z  = p; p += (size_t)Tt * Hh * Bb;
  float* AtT_b  = p; p += (size_t)Tt * Hh * Bb;
  float* hidden = p; p += (size_t)Bb * Tt * Hh;
  float* hT     = p; p += Hh * Bb;
  float* rh     = p; p += Hh * Bb;
  float* pre_z  = p; p += Hh * Bb;

  dim3 b256(256);
  k_proj<<<dim3(128, 8), b256, 0, stream>>>(x, wte, Wr,   br,   AtT_r);
  k_proj<<<dim3(128, 8), b256, 0, stream>>>(x, wte, Wz,   bz,   AtT_z);
  k_proj<<<dim3(128, 8), b256, 0, stream>>>(x, wte, Wbar, bbar, AtT_b);

  void* args[] = {&hT, &rh, &pre_z, &AtT_r, &AtT_z, &AtT_b,
                  (void*)&Wr, (void*)&Wz, (void*)&Wbar, (void*)&start, &hidden};
  hipLaunchCooperativeKernel((void*)k_recur, dim3(256), dim3(512), args, 0, stream);

  k_head<<<dim3(128, 32), b256, 0, stream>>>(hidden, Whead, bhead, out);
}

// Round 3
// 14526.680 us; speedup vs baseline: 1.7220x; 1.7220x over previous
//
#include <hip/hip_runtime.h>
#include <math.h>

#define Bb 64
#define Tt 256
#define Vv 4096
#define Ee 512
#define Hh 1024
#define NBLK 256

// ---------------- input projection: AtT[t][n][b] = sum_e wte[x[b,t]][e]*W[n][e] + bias[n]
__global__ __launch_bounds__(256) void k_proj(const int* __restrict__ x,
                                              const float* __restrict__ wte,
                                              const float* __restrict__ W,
                                              const float* __restrict__ bias,
                                              float* __restrict__ AtT) {
  __shared__ float As[16][132];
  __shared__ float Bs[16][132];
  int tid = threadIdx.x;
  int m0 = blockIdx.x * 128;
  int n0 = blockIdx.y * 128;
  int tm = tid & 15, tn = tid >> 4;
  float acc[8][8];
#pragma unroll
  for (int i = 0; i < 8; ++i)
#pragma unroll
    for (int j = 0; j < 8; ++j) acc[i][j] = 0.f;

  for (int k0 = 0; k0 < Ee; k0 += 16) {
#pragma unroll
    for (int p = 0; p < 2; ++p) {
      int id = tid + p * 256;
      int row = id >> 2, c4 = id & 3;
      int m = m0 + row;
      int tok = x[(m & 63) * Tt + (m >> 6)];
      float4 v = *(const float4*)(wte + tok * Ee + k0 + c4 * 4);
      As[c4 * 4 + 0][row] = v.x; As[c4 * 4 + 1][row] = v.y;
      As[c4 * 4 + 2][row] = v.z; As[c4 * 4 + 3][row] = v.w;
    }
#pragma unroll
    for (int p = 0; p < 2; ++p) {
      int id = tid + p * 256;
      int row = id >> 2, c4 = id & 3;
      float4 v = *(const float4*)(W + (n0 + row) * 1536 + k0 + c4 * 4);
      Bs[c4 * 4 + 0][row] = v.x; Bs[c4 * 4 + 1][row] = v.y;
      Bs[c4 * 4 + 2][row] = v.z; Bs[c4 * 4 + 3][row] = v.w;
    }
    __syncthreads();
#pragma unroll
    for (int kk = 0; kk < 16; ++kk) {
      float4 a0 = *(const float4*)&As[kk][tm * 8];
      float4 a1 = *(const float4*)&As[kk][tm * 8 + 4];
      float4 b0 = *(const float4*)&Bs[kk][tn * 8];
      float4 b1 = *(const float4*)&Bs[kk][tn * 8 + 4];
      float av[8] = {a0.x, a0.y, a0.z, a0.w, a1.x, a1.y, a1.z, a1.w};
      float bv[8] = {b0.x, b0.y, b0.z, b0.w, b1.x, b1.y, b1.z, b1.w};
#pragma unroll
      for (int i = 0; i < 8; ++i)
#pragma unroll
        for (int j = 0; j < 8; ++j)
          acc[i][j] = fmaf(av[i], bv[j], acc[i][j]);
    }
    __syncthreads();
  }
#pragma unroll
  for (int i = 0; i < 8; ++i) {
    int m = m0 + tm * 8 + i;
    int t = m >> 6, b = m & 63;
#pragma unroll
    for (int j = 0; j < 8; ++j) {
      int n = n0 + tn * 8 + j;
      AtT[(size_t)t * (Hh * Bb) + n * Bb + b] = acc[i][j] + bias[n];
    }
  }
}

// ---------------- head GEMM ------------------------------------------------------------
__global__ __launch_bounds__(256) void k_head(const float* __restrict__ A,
                                              const float* __restrict__ W,
                                              const float* __restrict__ bias,
                                              float* __restrict__ C) {
  __shared__ float As[16][132];
  __shared__ float Bs[16][132];
  int tid = threadIdx.x;
  int m0 = blockIdx.x * 128;
  int n0 = blockIdx.y * 128;
  int tm = tid & 15, tn = tid >> 4;
  float acc[8][8];
#pragma unroll
  for (int i = 0; i < 8; ++i)
#pragma unroll
    for (int j = 0; j < 8; ++j) acc[i][j] = 0.f;

  for (int k0 = 0; k0 < Hh; k0 += 16) {
#pragma unroll
    for (int p = 0; p < 2; ++p) {
      int id = tid + p * 256;
      int row = id >> 2, c4 = id & 3;
      float4 v = *(const float4*)(A + (size_t)(m0 + row) * Hh + k0 + c4 * 4);
      As[c4 * 4 + 0][row] = v.x; As[c4 * 4 + 1][row] = v.y;
      As[c4 * 4 + 2][row] = v.z; As[c4 * 4 + 3][row] = v.w;
    }
#pragma unroll
    for (int p = 0; p < 2; ++p) {
      int id = tid + p * 256;
      int row = id >> 2, c4 = id & 3;
      float4 v = *(const float4*)(W + (size_t)(n0 + row) * Hh + k0 + c4 * 4);
      Bs[c4 * 4 + 0][row] = v.x; Bs[c4 * 4 + 1][row] = v.y;
      Bs[c4 * 4 + 2][row] = v.z; Bs[c4 * 4 + 3][row] = v.w;
    }
    __syncthreads();
#pragma unroll
    for (int kk = 0; kk < 16; ++kk) {
      float4 a0 = *(const float4*)&As[kk][tm * 8];
      float4 a1 = *(const float4*)&As[kk][tm * 8 + 4];
      float4 b0 = *(const float4*)&Bs[kk][tn * 8];
      float4 b1 = *(const float4*)&Bs[kk][tn * 8 + 4];
      float av[8] = {a0.x, a0.y, a0.z, a0.w, a1.x, a1.y, a1.z, a1.w};
      float bv[8] = {b0.x, b0.y, b0.z, b0.w, b1.x, b1.y, b1.z, b1.w};
#pragma unroll
      for (int i = 0; i < 8; ++i)
#pragma unroll
        for (int j = 0; j < 8; ++j)
          acc[i][j] = fmaf(av[i], bv[j], acc[i][j]);
    }
    __syncthreads();
  }
#pragma unroll
  for (int i = 0; i < 8; ++i) {
    int m = m0 + tm * 8 + i;
#pragma unroll
    for (int jj = 0; jj < 2; ++jj) {
      int n = n0 + tn * 8 + jj * 4;
      float4 v;
      v.x = acc[i][jj * 4 + 0] + bias[n + 0];
      v.y = acc[i][jj * 4 + 1] + bias[n + 1];
      v.z = acc[i][jj * 4 + 2] + bias[n + 2];
      v.w = acc[i][jj * 4 + 3] + bias[n + 3];
      *(float4*)&C[(size_t)m * Vv + n] = v;
    }
  }
}

__global__ void k_zero(unsigned* __restrict__ cnt) { *cnt = 0u; }

// ---------------- fast grid barrier ----------------------------------------------------
// Monotonic counter; one release-add per block, relaxed spin, acquire on exit.
// AGENT scope => compiler emits the cross-XCD L2 writeback/invalidate needed (G16).
__device__ __forceinline__ void gbar(unsigned* cnt, unsigned target, int tid) {
  __syncthreads();   // drains all waves' vmem before tid0's release
  if (tid == 0) {
    __hip_atomic_fetch_add(cnt, 1u, __ATOMIC_RELEASE, __HIP_MEMORY_SCOPE_AGENT);
    while (__hip_atomic_load(cnt, __ATOMIC_RELAXED, __HIP_MEMORY_SCOPE_AGENT) < target)
      __builtin_amdgcn_s_sleep(1);
    (void)__hip_atomic_load(cnt, __ATOMIC_ACQUIRE, __HIP_MEMORY_SCOPE_AGENT);
  }
  __syncthreads();
}

// ---------------- persistent recurrence, custom barrier --------------------------------
// 256 blocks x 512 threads. Phase A: 8 cols/block over [r|z] (2048 cols);
// 8 waves k-split 128, LDS reduce. Phase B: 4 cols/block, hbar + fused update.
__global__ __launch_bounds__(512) void k_recur(float* __restrict__ hT,
                                               float* __restrict__ rh,
                                               float* __restrict__ pre_z,
                                               const float* __restrict__ AtT_r,
                                               const float* __restrict__ AtT_z,
                                               const float* __restrict__ AtT_b,
                                               const float* __restrict__ Wr,
                                               const float* __restrict__ Wz,
                                               const float* __restrict__ Wbar,
                                               const float* __restrict__ start,
                                               float* __restrict__ hidden,
                                               unsigned* __restrict__ cnt) {
  __shared__ float red[8 * 8 * 64];    // 16 KB
  __shared__ float lt[4 * 65];
  int tid = threadIdx.x;
  int lane = tid & 63;
  int wv = __builtin_amdgcn_readfirstlane(tid >> 6);
  int blk = blockIdx.x;
  unsigned bar = 0;

  {  // h0 = broadcast(start)
    int g = blk * 512 + tid;
    if (g < Hh * Bb) hT[g] = start[g >> 6];
  }
  gbar(cnt, (++bar) * NBLK, tid);

  for (int t = 0; t < Tt; ++t) {
    // ---------------- phase A: r,z preactivations ----------------
    {
      int n0 = blk * 8;                       // 0..2047 across [r|z]
      int k0 = wv * 128;
      const float* Wsel = (blk < 128) ? Wr : Wz;
      int nb = (blk < 128) ? n0 : n0 - 1024;
      const float* hk = hT + k0 * 64 + lane;
      const float* wbase = Wsel + (size_t)nb * 1536 + 512 + k0;
      float acc[8];
#pragma unroll
      for (int c = 0; c < 8; ++c) acc[c] = 0.f;
#pragma unroll 4
      for (int kk = 0; kk < 128; ++kk) {
        float vh = hk[kk * 64];
#pragma unroll
        for (int c = 0; c < 8; ++c)
          acc[c] = fmaf(wbase[(size_t)c * 1536 + kk], vh, acc[c]);
      }
#pragma unroll
      for (int c = 0; c < 8; ++c) red[(wv * 8 + c) * 64 + lane] = acc[c];
      __syncthreads();
      {
        int c = tid >> 6, b = tid & 63;       // 512 outputs, one per thread
        float s = 0.f;
#pragma unroll
        for (int w = 0; w < 8; ++w) s += red[(w * 8 + c) * 64 + b];
        int n = n0 + c;
        if (blk < 128) {
          s += AtT_r[(size_t)t * 65536 + n * 64 + b];
          float sg = 1.f / (1.f + __expf(-s));
          rh[n * 64 + b] = sg * hT[n * 64 + b];
        } else {
          int nz = n - 1024;
          s += AtT_z[(size_t)t * 65536 + nz * 64 + b];
          pre_z[nz * 64 + b] = s;
        }
      }
    }
    gbar(cnt, (++bar) * NBLK, tid);
    // ---------------- phase B: hbar + fused update ----------------
    {
      int n0 = blk * 4;                       // 0..1023
      int k0 = wv * 128;
      const float* hk = rh + k0 * 64 + lane;
      const float* wbase = Wbar + (size_t)n0 * 1536 + 512 + k0;
      float acc[4];
#pragma unroll
      for (int c = 0; c < 4; ++c) acc[c] = 0.f;
#pragma unroll 4
      for (int kk = 0; kk < 128; ++kk) {
        float vh = hk[kk * 64];
#pragma unroll
        for (int c = 0; c < 4; ++c)
          acc[c] = fmaf(wbase[(size_t)c * 1536 + kk], vh, acc[c]);
      }
#pragma unroll
      for (int c = 0; c < 4; ++c) red[(wv * 4 + c) * 64 + lane] = acc[c];
      __syncthreads();
      if (tid < 256) {
        int c = tid >> 6, b = tid & 63;
        float s = 0.f;
#pragma unroll
        for (int w = 0; w < 8; ++w) s += red[(w * 4 + c) * 64 + b];
        int n = n0 + c;
        s += AtT_b[(size_t)t * 65536 + n * 64 + b];
        float e = __expf(2.f * s);
        float hbt = 1.f - 2.f / (e + 1.f);    // tanh, saturation-safe
        float pz = pre_z[n * 64 + b];
        float z = 1.f / (1.f + __expf(-pz));
        float ho = hT[n * 64 + b];
        float hn = ho + z * (hbt - ho);
        hT[n * 64 + b] = hn;
        lt[c * 65 + b] = hn;
      }
      __syncthreads();
      if (tid < 64) {
        int b = tid;
        float4 v;
        v.x = lt[0 * 65 + b]; v.y = lt[1 * 65 + b];
        v.z = lt[2 * 65 + b]; v.w = lt[3 * 65 + b];
        *(float4*)&hidden[(size_t)b * (Tt * Hh) + (size_t)t * Hh + n0] = v;
      }
    }
    gbar(cnt, (++bar) * NBLK, tid);
  }
}

extern "C" void kernel_launch(void* const* d_in, const int* in_sizes, int n_in,
                              void* d_out, int out_size, void* d_ws, size_t ws_size,
                              hipStream_t stream) {
  (void)in_sizes; (void)n_in; (void)out_size; (void)ws_size;
  const int*   x     = (const int*)  d_in[0];
  const float* start = (const float*)d_in[1];
  const float* wte   = (const float*)d_in[2];
  const float* Wr    = (const float*)d_in[3];
  const float* br    = (const float*)d_in[4];
  const float* Wbar  = (const float*)d_in[5];
  const float* bbar  = (const float*)d_in[6];
  const float* Wz    = (const float*)d_in[7];
  const float* bz    = (const float*)d_in[8];
  const float* Whead = (const float*)d_in[9];
  const float* bhead = (const float*)d_in[10];
  float* out = (float*)d_out;

  float* p = (float*)d_ws;
  float* AtT_r  = p; p += (size_t)Tt * Hh * Bb;
  float* AtT_z  = p; p += (size_t)Tt * Hh * Bb;
  float* AtT_b  = p; p += (size_t)Tt * Hh * Bb;
  float* hidden = p; p += (size_t)Bb * Tt * Hh;
  float* hT     = p; p += Hh * Bb;
  float* rh     = p; p += Hh * Bb;
  float* pre_z  = p; p += Hh * Bb;
  unsigned* cnt = (unsigned*)p;

  dim3 b256(256);
  k_zero<<<dim3(1), dim3(1), 0, stream>>>(cnt);
  k_proj<<<dim3(128, 8), b256, 0, stream>>>(x, wte, Wr,   br,   AtT_r);
  k_proj<<<dim3(128, 8), b256, 0, stream>>>(x, wte, Wz,   bz,   AtT_z);
  k_proj<<<dim3(128, 8), b256, 0, stream>>>(x, wte, Wbar, bbar, AtT_b);

  void* args[] = {&hT, &rh, &pre_z, &AtT_r, &AtT_z, &AtT_b,
                  (void*)&Wr, (void*)&Wz, (void*)&Wbar, (void*)&start, &hidden, &cnt};
  hipLaunchCooperativeKernel((void*)k_recur, dim3(NBLK), dim3(512), args, 0, stream);

  k_head<<<dim3(128, 32), b256, 0, stream>>>(hidden, Whead, bhead, out);
}